// Round 4
// baseline (380.171 us; speedup 1.0000x reference)
//
#include <hip/hip_runtime.h>

#define EPSQ 1e-5f

typedef signed char i8;
using int4v = __attribute__((ext_vector_type(4))) int;

constexpr int DIM = 4096;

// ---------------------------------------------------------------------------
// async global->LDS, 16 B per lane. LDS dest = wave-uniform base + lane*16.
// ---------------------------------------------------------------------------
__device__ __forceinline__ void gload_lds16(const void* g, void* l) {
  __builtin_amdgcn_global_load_lds(
      (const __attribute__((address_space(1))) void*)(g),
      (__attribute__((address_space(3))) void*)(l), 16, 0, 0);
}

// ---------------------------------------------------------------------------
// k_prep, one launch, two block ranges:
//   [0, 4096)      : per-row symmetric i8 quant of X, rs[row] = max|x|/127
//   [4096, 6144)   : W1 = (i8)Vp (exact ternary) AND |U| partial sums in the
//                    same sweep, U = V - Vp*cos.  (|T| = |U|/|sin|; the 1/|st|
//                    factor is folded into the scalar mean in k_quantT, so
//                    NO per-element division anywhere.)
// ---------------------------------------------------------------------------
__global__ __launch_bounds__(256)
void k_prep(const float* __restrict__ X, const float* __restrict__ V,
            const float* __restrict__ Vp,
            const float* __restrict__ theta_p,
            i8* __restrict__ Xq, float* __restrict__ rs,
            i8* __restrict__ W1, float* __restrict__ partial) {
  __shared__ float wred[4];
  const int tid = threadIdx.x;
  const int b = blockIdx.x;
  if (b < 4096) {
    const int row = b;
    const float4* Xr = (const float4*)(X + (size_t)row * DIM);
    float4 f[4];
    float mx = 0.0f;
    #pragma unroll
    for (int t = 0; t < 4; ++t) {
      f[t] = Xr[tid + t * 256];
      mx = fmaxf(mx, fmaxf(fmaxf(fabsf(f[t].x), fabsf(f[t].y)),
                           fmaxf(fabsf(f[t].z), fabsf(f[t].w))));
    }
    #pragma unroll
    for (int off = 32; off > 0; off >>= 1) mx = fmaxf(mx, __shfl_down(mx, off, 64));
    int lane = tid & 63, w = tid >> 6;
    if (lane == 0) wred[w] = mx;
    __syncthreads();
    mx = fmaxf(fmaxf(wred[0], wred[1]), fmaxf(wred[2], wred[3]));
    mx = fmaxf(mx, 1e-30f);
    float rsv = mx / 127.0f;
    if (tid == 0) rs[row] = rsv;
    float inv = 1.0f / rsv;
    char4* Xo = (char4*)(Xq + (size_t)row * DIM);
    #pragma unroll
    for (int t = 0; t < 4; ++t) {
      char4 qv;
      qv.x = (i8)fminf(fmaxf(rintf(f[t].x * inv), -127.0f), 127.0f);
      qv.y = (i8)fminf(fmaxf(rintf(f[t].y * inv), -127.0f), 127.0f);
      qv.z = (i8)fminf(fmaxf(rintf(f[t].z * inv), -127.0f), 127.0f);
      qv.w = (i8)fminf(fmaxf(rintf(f[t].w * inv), -127.0f), 127.0f);
      Xo[tid + t * 256] = qv;
    }
  } else {
    // ---- W1 conversion + |U| partial sums, single V/Vp sweep, div-free ----
    float ct = cosf(theta_p[0]);
    const float4* V4  = (const float4*)V;
    const float4* Vp4 = (const float4*)Vp;
    char4* W1o = (char4*)W1;
    float acc = 0.0f;
    const int total4 = DIM * DIM / 4;
    const int stride = 2048 * 256;
    for (int i = (b - 4096) * 256 + tid; i < total4; i += stride) {
      float4 vp = Vp4[i];
      float4 v  = V4[i];
      char4 w1;
      w1.x = (i8)vp.x; w1.y = (i8)vp.y; w1.z = (i8)vp.z; w1.w = (i8)vp.w;
      W1o[i] = w1;
      acc += fabsf(v.x - vp.x * ct) + fabsf(v.y - vp.y * ct)
           + fabsf(v.z - vp.z * ct) + fabsf(v.w - vp.w * ct);
    }
    #pragma unroll
    for (int off = 32; off > 0; off >>= 1) acc += __shfl_down(acc, off, 64);
    int lane = tid & 63, w = tid >> 6;
    if (lane == 0) wred[w] = acc;
    __syncthreads();
    if (tid == 0) partial[b - 4096] = wred[0] + wred[1] + wred[2] + wred[3];
  }
}

// ---------------------------------------------------------------------------
// k_quantT: only does work when bias != 0 (W2 unused otherwise).
// mean|T| = (sum|U|/N)/|st|;  W2 = clamp(round(U * (scale/st)), -1, 1).
// One scalar division per thread; the per-element path is fma+mul+rint+clamp.
// ---------------------------------------------------------------------------
__global__ __launch_bounds__(256)
void k_quantT(const float* __restrict__ V, const float* __restrict__ Vp,
              const float* __restrict__ theta_p, const float* __restrict__ bias_p,
              const float* __restrict__ partial, i8* __restrict__ W2) {
  if (bias_p[0] == 0.0f) return;
  __shared__ float wred[4];
  __shared__ float stot;
  const int tid = threadIdx.x;
  float s = 0.0f;
  #pragma unroll
  for (int i = 0; i < 8; ++i) s += partial[tid + i * 256];
  #pragma unroll
  for (int off = 32; off > 0; off >>= 1) s += __shfl_down(s, off, 64);
  int lane = tid & 63, w = tid >> 6;
  if (lane == 0) wred[w] = s;
  __syncthreads();
  if (tid == 0) stot = wred[0] + wred[1] + wred[2] + wred[3];
  __syncthreads();
  float ctv = cosf(theta_p[0]);
  float stv = sinf(theta_p[0]);
  float meanT = fmaxf((stot / 16777216.0f) / fabsf(stv), EPSQ);
  float f = 1.0f / (meanT * stv);          // = scale/st (sign of st included)
  const float4* V4  = (const float4*)V;
  const float4* Vp4 = (const float4*)Vp;
  char4* W2o = (char4*)W2;
  const int total4 = DIM * DIM / 4;
  const int stride = 2048 * 256;
  for (int i = blockIdx.x * 256 + tid; i < total4; i += stride) {
    float4 v = V4[i], vp = Vp4[i];
    char4 w2;
    w2.x = (i8)fminf(fmaxf(rintf((v.x - vp.x * ctv) * f), -1.0f), 1.0f);
    w2.y = (i8)fminf(fmaxf(rintf((v.y - vp.y * ctv) * f), -1.0f), 1.0f);
    w2.z = (i8)fminf(fmaxf(rintf((v.z - vp.z * ctv) * f), -1.0f), 1.0f);
    w2.w = (i8)fminf(fmaxf(rintf((v.w - vp.w * ctv) * f), -1.0f), 1.0f);
    W2o[i] = w2;
  }
}

// ---------------------------------------------------------------------------
// i8 MFMA GEMM, 256x256 tile, BK=128 B, 8 waves (2Mx4N), 128 KiB dbuf LDS.
// 2 phases per K-tile; B fragments held in REGISTERS across both phases
// (minimal LDS reads: 16 A + 8 B b128/wave/tile = 192 KiB/CU/tile < MFMA
// pipe time).  2 barriers/tile (was 5).  Counted vmcnt, never 0 in the
// main loop:
//   stage order per tile t (into buf for t+1): ph0: A[h0],B[h0]; ph1: B[h1],A[h1]
//   FIFO at t.ph0 entry: [A_t h0, B_t h0, B_t h1, A_t h1] (8 loads)
//     ph0 needs A[h0]+B(all) = oldest 6 -> vmcnt(2); then stages 4 -> 6
//     ph1 needs A[h1]                   -> vmcnt(4); then stages 4 -> 8
//   Every load has >=1 full phase (~1300 cyc) of cover vs ~900 cyc HBM lat.
//   Drain to 0 only in the peeled last tile.
// Two fused passes (sign GEMM vs W2, main GEMM vs W1); pass-0 result kept
// as sign-mask VGPRs, single C write at the end.
// ---------------------------------------------------------------------------

#define SA(AG, KT, DST, MHH) do {                                              \
    _Pragma("unroll")                                                          \
    for (int jj = 0; jj < 2; ++jj) {                                           \
      int br = (MHH) * 64 + jj * 128 + w * 8;                                  \
      gload_lds16((AG) + (size_t)br * DIM + (KT) + goff, (DST) + br * 128);    \
    }                                                                          \
  } while (0)

#define SB(BG, KT, DST, NHH) do {                                              \
    _Pragma("unroll")                                                          \
    for (int jj = 0; jj < 2; ++jj) {                                           \
      int br = (w >> 1) * 64 + (NHH) * 32 + ((w * 2 + jj) & 3) * 8;            \
      gload_lds16((BG) + (size_t)br * DIM + (KT) + goff, (DST) + br * 128);    \
    }                                                                          \
  } while (0)

#define PH(As_, Bs_, MH, VMSTR, ...) do {                                      \
    asm volatile("s_waitcnt vmcnt(" VMSTR ")" ::: "memory");                   \
    __builtin_amdgcn_s_barrier();                                              \
    asm volatile("" ::: "memory");                                             \
    _Pragma("unroll")                                                          \
    for (int i4 = 0; i4 < 4; ++i4) {                                           \
      const i8* ap = (As_) + arow + ((MH) * 4 + i4) * 2048;                    \
      af[i4][0] = *(const int4v*)(ap + swz0);                                  \
      af[i4][1] = *(const int4v*)(ap + swz1);                                  \
    }                                                                          \
    if ((MH) == 0) {                                                           \
      _Pragma("unroll")                                                        \
      for (int j = 0; j < 4; ++j) {                                            \
        const i8* bp = (Bs_) + brow + j * 2048;                                \
        bf[j][0] = *(const int4v*)(bp + swz0);                                 \
        bf[j][1] = *(const int4v*)(bp + swz1);                                 \
      }                                                                        \
    }                                                                          \
    __VA_ARGS__;                                                               \
    asm volatile("s_waitcnt lgkmcnt(0)" ::: "memory");                         \
    __builtin_amdgcn_sched_barrier(0);                                         \
    __builtin_amdgcn_s_setprio(1);                                             \
    _Pragma("unroll")                                                          \
    for (int i4 = 0; i4 < 4; ++i4)                                             \
      _Pragma("unroll")                                                        \
      for (int j = 0; j < 4; ++j) {                                            \
        acc[(MH)*4 + i4][j] = __builtin_amdgcn_mfma_i32_16x16x64_i8(           \
            af[i4][0], bf[j][0], acc[(MH)*4 + i4][j], 0, 0, 0);                \
        acc[(MH)*4 + i4][j] = __builtin_amdgcn_mfma_i32_16x16x64_i8(           \
            af[i4][1], bf[j][1], acc[(MH)*4 + i4][j], 0, 0, 0);                \
      }                                                                        \
    __builtin_amdgcn_s_setprio(0);                                             \
  } while (0)

__global__ __launch_bounds__(512, 2)
void k_gemm(const i8* __restrict__ A, const i8* __restrict__ B1,
            const i8* __restrict__ B2, float* __restrict__ C,
            const float* __restrict__ rs, const float* __restrict__ theta_p,
            const float* __restrict__ bias_p) {
  __shared__ i8 sm[131072];   // buf0: [As 32K | Bs 32K] @0, buf1 @65536

  const int tid  = threadIdx.x;
  const int lane = tid & 63;
  const int w    = tid >> 6;
  const int l15  = lane & 15;
  const int kq   = lane >> 4;          // k-quad 0..3
  const int wm   = (w >> 2) * 128;     // 2 waves in M
  const int wn   = (w & 3) * 64;       // 4 waves in N
  const int bm   = blockIdx.y * 256;
  const int bn   = blockIdx.x * 256;

  // per-lane global offset: row group of 8, chunk-XOR swizzle (store-side)
  const int goff = (lane >> 3) * DIM + (((lane & 7) ^ (lane >> 3)) << 4);

  const int swz0 = ((0 * 4 + kq) ^ (l15 & 7)) * 16;   // k-chunk swizzle, s=0
  const int swz1 = ((1 * 4 + kq) ^ (l15 & 7)) * 16;   // s=1
  const int arow = (wm + l15) * 128;
  const int brow = (wn + l15) * 128;

  const float biasv = bias_p[0];
  const int npass = (biasv != 0.0f) ? 2 : 1;
  const float ct = cosf(theta_p[0]);

  // sign masks from pass 0 (bit b = i*16 + j*4 + r); stay 0 when npass==1
  unsigned pm[4] = {0u, 0u, 0u, 0u};
  unsigned nm[4] = {0u, 0u, 0u, 0u};

  for (int pass = 0; pass < npass; ++pass) {
    const bool signp = (npass == 2 && pass == 0);
    const i8* Ag = A + (size_t)bm * DIM;
    const i8* Bg = (signp ? B2 : B1) + (size_t)bn * DIM;

    int4v acc[8][4] = {};
    int4v af[4][2], bf[4][2];

    // ---- prologue: stage tile 0 into buf0, order A0,B0,B1,A1 (no drain) ----
    SA(Ag, 0, sm, 0);
    SB(Bg, 0, sm + 32768, 0);
    SB(Bg, 0, sm + 32768, 1);
    SA(Ag, 0, sm, 1);

    #pragma unroll 2
    for (int t = 0; t < 31; ++t) {
      const i8* As = sm + (t & 1) * 65536;
      const i8* Bs = As + 32768;
      i8* An = sm + ((t + 1) & 1) * 65536;
      i8* Bn = An + 32768;
      const int ktn = (t + 1) * 128;
      PH(As, Bs, 0, "2", SA(Ag, ktn, An, 0); SB(Bg, ktn, Bn, 0));
      PH(As, Bs, 1, "4", SB(Bg, ktn, Bn, 1); SA(Ag, ktn, An, 1));
    }
    {   // ---- peeled last tile (t=31, buf1): drain 2 -> 0 ----
      const i8* As = sm + 65536;
      const i8* Bs = As + 32768;
      PH(As, Bs, 0, "2", ((void)0));
      PH(As, Bs, 1, "0", ((void)0));
    }

    if (signp) {
      // ---- pass 0: pack sign(acc) into mask registers, no global I/O ----
      #pragma unroll
      for (int i = 0; i < 8; ++i)
        #pragma unroll
        for (int j = 0; j < 4; ++j)
          #pragma unroll
          for (int r = 0; r < 4; ++r) {
            int v = acc[i][j][r];
            int b = i * 16 + j * 4 + r;
            pm[b >> 5] |= (unsigned)(v > 0) << (b & 31);
            nm[b >> 5] |= (unsigned)(v < 0) << (b & 31);
          }
    } else {
      // ---- final epilogue: C = ct*rs*acc + sign_mask * bias (single write)
      // C/D layout: row = kq*4 + reg, col = lane&15 per 16x16 tile.
      #pragma unroll
      for (int i = 0; i < 8; ++i) {
        int mbase = bm + wm + i * 16 + kq * 4;
        float sc[4];
        #pragma unroll
        for (int r = 0; r < 4; ++r) sc[r] = ct * rs[mbase + r];
        #pragma unroll
        for (int j = 0; j < 4; ++j) {
          int n = bn + wn + j * 16 + l15;
          #pragma unroll
          for (int r = 0; r < 4; ++r) {
            int b = i * 16 + j * 4 + r;
            float sgn = ((pm[b >> 5] >> (b & 31)) & 1u) ? biasv
                      : (((nm[b >> 5] >> (b & 31)) & 1u) ? -biasv : 0.0f);
            C[(size_t)(mbase + r) * DIM + n] = sc[r] * (float)acc[i][j][r] + sgn;
          }
        }
      }
    }
  }
}

// ---------------------------------------------------------------------------
extern "C" void kernel_launch(void* const* d_in, const int* in_sizes, int n_in,
                              void* d_out, int out_size, void* d_ws, size_t ws_size,
                              hipStream_t stream) {
  const float* V     = (const float*)d_in[0];
  const float* Vp    = (const float*)d_in[1];
  const float* X     = (const float*)d_in[2];
  const float* theta = (const float*)d_in[3];
  const float* bias  = (const float*)d_in[4];
  float* out = (float*)d_out;

  const size_t SZ = (size_t)DIM * DIM;
  char* ws = (char*)d_ws;
  float* rs      = (float*)ws;                    // 16 KiB row scales
  float* partial = (float*)(ws + 16384);          // 8 KiB |U| partials
  i8* Xq = (i8*)(ws + 16384 + 8192);              // 16 MiB
  i8* W1 = Xq + SZ;                               // 16 MiB (V_p i8, exact)
  i8* W2 = W1 + SZ;                               // 16 MiB (Tq i8, bias!=0 only)

  k_prep<<<6144, 256, 0, stream>>>(X, V, Vp, theta, Xq, rs, W1, partial);
  k_quantT<<<2048, 256, 0, stream>>>(V, Vp, theta, bias, partial, W2);
  k_gemm<<<dim3(16, 16), 512, 0, stream>>>(Xq, W1, W2, out, rs, theta, bias);
}

// Round 5
// 297.517 us; speedup vs baseline: 1.2778x; 1.2778x over previous
//
#include <hip/hip_runtime.h>

#define EPSQ 1e-5f

typedef signed char i8;
using int4v = __attribute__((ext_vector_type(4))) int;

constexpr int DIM = 4096;

// ---------------------------------------------------------------------------
// async global->LDS, 16 B per lane. LDS dest = wave-uniform base + lane*16.
// ---------------------------------------------------------------------------
__device__ __forceinline__ void gload_lds16(const void* g, void* l) {
  __builtin_amdgcn_global_load_lds(
      (const __attribute__((address_space(1))) void*)(g),
      (__attribute__((address_space(3))) void*)(l), 16, 0, 0);
}

// ---------------------------------------------------------------------------
// k_prep, one launch, two block ranges:
//   [0, 4096)      : per-row symmetric i8 quant of X, rs[row] = max|x|/127
//   [4096, 8192)   : W1 = (i8)Vp (exact ternary) AND |U| partial sums in the
//                    same sweep, U = V - Vp*cos.  (|T| = |U|/|sin|; 1/|st| is
//                    folded into the scalar mean in k_quantT -> div-free.)
// ---------------------------------------------------------------------------
__global__ __launch_bounds__(256)
void k_prep(const float* __restrict__ X, const float* __restrict__ V,
            const float* __restrict__ Vp,
            const float* __restrict__ theta_p,
            i8* __restrict__ Xq, float* __restrict__ rs,
            i8* __restrict__ W1, float* __restrict__ partial) {
  __shared__ float wred[4];
  const int tid = threadIdx.x;
  const int b = blockIdx.x;
  if (b < 4096) {
    const int row = b;
    const float4* Xr = (const float4*)(X + (size_t)row * DIM);
    float4 f[4];
    float mx = 0.0f;
    #pragma unroll
    for (int t = 0; t < 4; ++t) {
      f[t] = Xr[tid + t * 256];
      mx = fmaxf(mx, fmaxf(fmaxf(fabsf(f[t].x), fabsf(f[t].y)),
                           fmaxf(fabsf(f[t].z), fabsf(f[t].w))));
    }
    #pragma unroll
    for (int off = 32; off > 0; off >>= 1) mx = fmaxf(mx, __shfl_down(mx, off, 64));
    int lane = tid & 63, w = tid >> 6;
    if (lane == 0) wred[w] = mx;
    __syncthreads();
    mx = fmaxf(fmaxf(wred[0], wred[1]), fmaxf(wred[2], wred[3]));
    mx = fmaxf(mx, 1e-30f);
    float rsv = mx / 127.0f;
    if (tid == 0) rs[row] = rsv;
    float inv = 1.0f / rsv;
    char4* Xo = (char4*)(Xq + (size_t)row * DIM);
    #pragma unroll
    for (int t = 0; t < 4; ++t) {
      char4 qv;
      qv.x = (i8)fminf(fmaxf(rintf(f[t].x * inv), -127.0f), 127.0f);
      qv.y = (i8)fminf(fmaxf(rintf(f[t].y * inv), -127.0f), 127.0f);
      qv.z = (i8)fminf(fmaxf(rintf(f[t].z * inv), -127.0f), 127.0f);
      qv.w = (i8)fminf(fmaxf(rintf(f[t].w * inv), -127.0f), 127.0f);
      Xo[tid + t * 256] = qv;
    }
  } else {
    // ---- W1 conversion + |U| partial sums; 4096 blocks, 2-way ILP ----
    float ct = cosf(theta_p[0]);
    const float4* V4  = (const float4*)V;
    const float4* Vp4 = (const float4*)Vp;
    char4* W1o = (char4*)W1;
    float acc0 = 0.0f, acc1 = 0.0f;
    const int total4 = DIM * DIM / 4;          // 4,194,304
    const int nthr   = 4096 * 256;             // 1,048,576 -> 4 iters/thread
    const int base   = (b - 4096) * 256 + tid;
    #pragma unroll 2
    for (int i = base; i < total4; i += nthr) {
      float4 vp = Vp4[i];
      float4 v  = V4[i];
      char4 w1;
      w1.x = (i8)vp.x; w1.y = (i8)vp.y; w1.z = (i8)vp.z; w1.w = (i8)vp.w;
      W1o[i] = w1;
      acc0 += fabsf(v.x - vp.x * ct) + fabsf(v.y - vp.y * ct);
      acc1 += fabsf(v.z - vp.z * ct) + fabsf(v.w - vp.w * ct);
    }
    float acc = acc0 + acc1;
    #pragma unroll
    for (int off = 32; off > 0; off >>= 1) acc += __shfl_down(acc, off, 64);
    int lane = tid & 63, w = tid >> 6;
    if (lane == 0) wred[w] = acc;
    __syncthreads();
    if (tid == 0) partial[b - 4096] = wred[0] + wred[1] + wred[2] + wred[3];
  }
}

// ---------------------------------------------------------------------------
// k_quantT: only does work when bias != 0 (W2 unused otherwise).
// mean|T| = (sum|U|/N)/|st|;  W2 = clamp(round(U * (scale/st)), -1, 1).
// ---------------------------------------------------------------------------
__global__ __launch_bounds__(256)
void k_quantT(const float* __restrict__ V, const float* __restrict__ Vp,
              const float* __restrict__ theta_p, const float* __restrict__ bias_p,
              const float* __restrict__ partial, i8* __restrict__ W2) {
  if (bias_p[0] == 0.0f) return;
  __shared__ float wred[4];
  __shared__ float stot;
  const int tid = threadIdx.x;
  float s = 0.0f;
  #pragma unroll
  for (int i = 0; i < 16; ++i) s += partial[tid + i * 256];
  #pragma unroll
  for (int off = 32; off > 0; off >>= 1) s += __shfl_down(s, off, 64);
  int lane = tid & 63, w = tid >> 6;
  if (lane == 0) wred[w] = s;
  __syncthreads();
  if (tid == 0) stot = wred[0] + wred[1] + wred[2] + wred[3];
  __syncthreads();
  float ctv = cosf(theta_p[0]);
  float stv = sinf(theta_p[0]);
  float meanT = fmaxf((stot / 16777216.0f) / fabsf(stv), EPSQ);
  float f = 1.0f / (meanT * stv);          // = scale/st (sign of st included)
  const float4* V4  = (const float4*)V;
  const float4* Vp4 = (const float4*)Vp;
  char4* W2o = (char4*)W2;
  const int total4 = DIM * DIM / 4;
  const int nthr   = 4096 * 256;           // 4 iters/thread
  #pragma unroll 2
  for (int i = blockIdx.x * 256 + tid; i < total4; i += nthr) {
    float4 v = V4[i], vp = Vp4[i];
    char4 w2;
    w2.x = (i8)fminf(fmaxf(rintf((v.x - vp.x * ctv) * f), -1.0f), 1.0f);
    w2.y = (i8)fminf(fmaxf(rintf((v.y - vp.y * ctv) * f), -1.0f), 1.0f);
    w2.z = (i8)fminf(fmaxf(rintf((v.z - vp.z * ctv) * f), -1.0f), 1.0f);
    w2.w = (i8)fminf(fmaxf(rintf((v.w - vp.w * ctv) * f), -1.0f), 1.0f);
    W2o[i] = w2;
  }
}

// ---------------------------------------------------------------------------
// i8 MFMA GEMM, 256x256 tile, BK=128 bytes, 8 waves (2Mx4N), 128 KiB dbuf LDS.
// Round-3-measured schedule (100us for both passes): ds_reads + full
// next-tile stage issued BEFORE the phase barrier, lgkmcnt(0) +
// setprio-wrapped 16-MFMA cluster after it, vmcnt(0) once per tile at q3.
// Register budget note: acc[8][4] = 128 AGPR/lane is fixed; at
// __launch_bounds__(512,2) only 128 VGPRs remain.  The t-loop is therefore
// NOT unrolled (unroll-2 doubled live staging addresses/fragments and caused
// scratch spills: +30..+142 MB of FETCH/WRITE in rounds 3/4).
// ---------------------------------------------------------------------------
__global__ __launch_bounds__(512, 2)
void k_gemm(const i8* __restrict__ A, const i8* __restrict__ B1,
            const i8* __restrict__ B2, float* __restrict__ C,
            const float* __restrict__ rs, const float* __restrict__ theta_p,
            const float* __restrict__ bias_p) {
  __shared__ i8 sm[131072];   // [As0 32K | Bs0 32K | As1 32K | Bs1 32K]

  const int tid  = threadIdx.x;
  const int lane = tid & 63;
  const int w    = tid >> 6;
  const int l15  = lane & 15;
  const int kq   = lane >> 4;          // k-quad 0..3
  const int wm   = (w >> 2) * 128;     // 2 waves in M
  const int wn   = (w & 3) * 64;       // 4 waves in N
  const int bm   = blockIdx.y * 256;
  const int bn   = blockIdx.x * 256;

  // staging geometry: tile = 256 rows x 8 chunks(16B); 4 issue lines x 512 thr
  int offg[4];
  #pragma unroll
  for (int ln = 0; ln < 4; ++ln) {
    int p = ln * 512 + tid;
    int r = p >> 3;
    int c = (p & 7) ^ (r & 7);          // XOR chunk swizzle (store-side inverse)
    offg[ln] = r * DIM + c * 16;
  }

  const int swz0 = ((0 * 4 + kq) ^ (l15 & 7)) * 16;   // k-chunk swizzle, s=0
  const int swz1 = ((1 * 4 + kq) ^ (l15 & 7)) * 16;   // s=1
  const int arow = (wm + l15) * 128;
  const int brow = (wn + l15) * 128;

  const float biasv = bias_p[0];
  const int npass = (biasv != 0.0f) ? 2 : 1;
  const float ct = cosf(theta_p[0]);

  // sign masks from pass 0 (bit b = i*16 + j*4 + r); stay 0 when npass==1
  unsigned pm[4] = {0u, 0u, 0u, 0u};
  unsigned nm[4] = {0u, 0u, 0u, 0u};

  for (int pass = 0; pass < npass; ++pass) {
    const bool signp = (npass == 2 && pass == 0);
    const i8* Ag = A + (size_t)bm * DIM;
    const i8* Bg = (signp ? B2 : B1) + (size_t)bn * DIM;

    int4v acc[8][4] = {};

    // ---- prologue: stage tile 0 into buf0, full drain once ----
    #pragma unroll
    for (int ln = 0; ln < 4; ++ln) {
      const int sb = (ln * 512 + w * 64) * 16;   // wave-uniform LDS base
      gload_lds16(Ag + offg[ln], sm + sb);
      gload_lds16(Bg + offg[ln], sm + 32768 + sb);
    }
    asm volatile("s_waitcnt vmcnt(0)" ::: "memory");
    __builtin_amdgcn_s_barrier();

    #pragma unroll 1
    for (int t = 0; t < 32; ++t) {
      const i8* As = sm + (t & 1) * 65536;
      const i8* Bs = As + 32768;
      i8* Asta = sm + ((t + 1) & 1) * 65536;
      i8* Bsta = Asta + 32768;
      const bool dostage = (t + 1 < 32);
      const int ktn = (t + 1) * 128;

      int4v af[4][2], bf[2][2];
      #pragma unroll
      for (int q = 0; q < 4; ++q) {
        const int mh = q >> 1, nh = q & 1;     // quadrant order (0,0)(0,1)(1,0)(1,1)
        if (nh == 0) {                         // A frags reused across two phases
          #pragma unroll
          for (int i4 = 0; i4 < 4; ++i4) {
            af[i4][0] = *(const int4v*)(As + arow + (mh * 4 + i4) * 2048 + swz0);
            af[i4][1] = *(const int4v*)(As + arow + (mh * 4 + i4) * 2048 + swz1);
          }
        }
        #pragma unroll
        for (int j2 = 0; j2 < 2; ++j2) {
          bf[j2][0] = *(const int4v*)(Bs + brow + (nh * 2 + j2) * 2048 + swz0);
          bf[j2][1] = *(const int4v*)(Bs + brow + (nh * 2 + j2) * 2048 + swz1);
        }
        if (q == 0 && dostage) {
          // issue the whole next tile now; lands before the vmcnt at q==3
          #pragma unroll
          for (int ln = 0; ln < 4; ++ln) {
            const int sb = (ln * 512 + w * 64) * 16;
            gload_lds16(Ag + ktn + offg[ln], Asta + sb);
            gload_lds16(Bg + ktn + offg[ln], Bsta + sb);
          }
        }
        __builtin_amdgcn_s_barrier();
        asm volatile("s_waitcnt lgkmcnt(0)" ::: "memory");
        __builtin_amdgcn_sched_barrier(0);     // keep MFMA below the wait
        __builtin_amdgcn_s_setprio(1);
        #pragma unroll
        for (int i4 = 0; i4 < 4; ++i4) {
          #pragma unroll
          for (int j2 = 0; j2 < 2; ++j2) {
            acc[mh * 4 + i4][nh * 2 + j2] = __builtin_amdgcn_mfma_i32_16x16x64_i8(
                af[i4][0], bf[j2][0], acc[mh * 4 + i4][nh * 2 + j2], 0, 0, 0);
            acc[mh * 4 + i4][nh * 2 + j2] = __builtin_amdgcn_mfma_i32_16x16x64_i8(
                af[i4][1], bf[j2][1], acc[mh * 4 + i4][nh * 2 + j2], 0, 0, 0);
          }
        }
        __builtin_amdgcn_s_setprio(0);
        if (q == 3) asm volatile("s_waitcnt vmcnt(0)" ::: "memory");
        __builtin_amdgcn_s_barrier();
      }
    }

    if (signp) {
      // ---- pass 0: pack sign(acc) into mask registers, no global I/O ----
      #pragma unroll
      for (int i = 0; i < 8; ++i)
        #pragma unroll
        for (int j = 0; j < 4; ++j)
          #pragma unroll
          for (int r = 0; r < 4; ++r) {
            int v = acc[i][j][r];
            int b = i * 16 + j * 4 + r;
            pm[b >> 5] |= (unsigned)(v > 0) << (b & 31);
            nm[b >> 5] |= (unsigned)(v < 0) << (b & 31);
          }
    } else {
      // ---- final epilogue: C = ct*rs*acc + sign_mask * bias (single write)
      // C/D layout: row = kq*4 + reg, col = lane&15 per 16x16 tile.
      #pragma unroll
      for (int i = 0; i < 8; ++i) {
        int mbase = bm + wm + i * 16 + kq * 4;
        float sc[4];
        #pragma unroll
        for (int r = 0; r < 4; ++r) sc[r] = ct * rs[mbase + r];
        #pragma unroll
        for (int j = 0; j < 4; ++j) {
          int n = bn + wn + j * 16 + l15;
          #pragma unroll
          for (int r = 0; r < 4; ++r) {
            int b = i * 16 + j * 4 + r;
            float sgn = ((pm[b >> 5] >> (b & 31)) & 1u) ? biasv
                      : (((nm[b >> 5] >> (b & 31)) & 1u) ? -biasv : 0.0f);
            C[(size_t)(mbase + r) * DIM + n] = sc[r] * (float)acc[i][j][r] + sgn;
          }
        }
      }
    }
  }
}

// ---------------------------------------------------------------------------
extern "C" void kernel_launch(void* const* d_in, const int* in_sizes, int n_in,
                              void* d_out, int out_size, void* d_ws, size_t ws_size,
                              hipStream_t stream) {
  const float* V     = (const float*)d_in[0];
  const float* Vp    = (const float*)d_in[1];
  const float* X     = (const float*)d_in[2];
  const float* theta = (const float*)d_in[3];
  const float* bias  = (const float*)d_in[4];
  float* out = (float*)d_out;

  const size_t SZ = (size_t)DIM * DIM;
  char* ws = (char*)d_ws;
  float* rs      = (float*)ws;                    // 16 KiB row scales
  float* partial = (float*)(ws + 16384);          // 16 KiB |U| partials (4096)
  i8* Xq = (i8*)(ws + 16384 + 16384);             // 16 MiB
  i8* W1 = Xq + SZ;                               // 16 MiB (V_p i8, exact)
  i8* W2 = W1 + SZ;                               // 16 MiB (Tq i8, bias!=0 only)

  k_prep<<<8192, 256, 0, stream>>>(X, V, Vp, theta, Xq, rs, W1, partial);
  k_quantT<<<4096, 256, 0, stream>>>(V, Vp, theta, bias, partial, W2);
  k_gemm<<<dim3(16, 16), 512, 0, stream>>>(Xq, W1, W2, out, rs, theta, bias);
}